// Round 6
// baseline (126.628 us; speedup 1.0000x reference)
//
#include <hip/hip_runtime.h>

#define NN 1024
#define NROWS 2048

#define NEG_INF (-__builtin_huge_valf())

__device__ __forceinline__ float orf(float v, unsigned int m) {
    return __uint_as_float(__float_as_uint(v) | m);
}

// ---------------- K1: msg2 = feat @ w2 + b2 ----------------------------------
// grid 256 x 512 thr; 8 rows/block.
__global__ __launch_bounds__(512) void k1_msg2(
    const float* __restrict__ feat, const float* __restrict__ w2,
    const float* __restrict__ b2, float* __restrict__ msg2)
{
    __shared__ float sf[8][128];
    const int tid = threadIdx.x;
    const int rb = blockIdx.x * 8;
    if (tid < 256) {
        int r = tid >> 5, c = (tid & 31) * 4;
        *reinterpret_cast<float4*>(&sf[r][c]) =
            *reinterpret_cast<const float4*>(feat + (size_t)(rb + r)*128 + c);
    }
    __syncthreads();
    const int m = tid & 127, rh = tid >> 7;     // rh 0..3 -> rows rh*2, rh*2+1
    float a0 = 0.f, a1 = 0.f;
    #pragma unroll 4
    for (int k = 0; k < 128; ++k) {
        float wv = w2[k*128 + m];
        a0 = fmaf(sf[rh*2][k],   wv, a0);
        a1 = fmaf(sf[rh*2+1][k], wv, a1);
    }
    const float bb = b2[m];
    msg2[(size_t)(rb + rh*2)*128 + m]     = a0 + bb;
    msg2[(size_t)(rb + rh*2 + 1)*128 + m] = a1 + bb;
}

// ---------------- K2: everything else, fully block-local ---------------------
// grid 256 x 512 thr; block owns 8 flat output rows (b = rb>>10, j0 = rb&1023).
// A': msg1,h1 for 8 rows -> LDS.  B: masked max over all 1024 i via 8 LDS
// tiles (reg-staged, issue-early/write-late).  C: relu+MLP+h1 add, in-block.
struct K2Shared {
    union {
        float sm2[128][128];                                  // 64 KB msg2 tile
        struct { float sx[8][128]; float sh0[8][32];
                 float sh1[8][64]; float sh2[8][64]; } c;     // 9 KB MLP
    } u;
    unsigned int adjm[128][8];    // 4 KB NaN-poison masks for current tile
    float m1[8][128];             // 4 KB msg1 rows
    float hh[8][128];             // 4 KB h1 rows
    float scratch[256][4];        // 4 KB ih-combine
};

__global__ __launch_bounds__(512) void k2_fused(
    const float* __restrict__ feat, const float* __restrict__ adj,
    const float* __restrict__ msg2,
    const float* __restrict__ w1, const float* __restrict__ b1,
    const float* __restrict__ wo, const float* __restrict__ bo,
    const float* __restrict__ wm0, const float* __restrict__ bm0,
    const float* __restrict__ wm1, const float* __restrict__ bm1,
    const float* __restrict__ wm2, const float* __restrict__ bm2,
    const float* __restrict__ wm3, const float* __restrict__ bm3,
    float* __restrict__ out)
{
    __shared__ K2Shared sh;
    const int tid = threadIdx.x;
    const int rb = blockIdx.x * 8;          // flat row base
    const int b  = rb >> 10;
    const int j0 = rb & 1023;

    // ---- stage feat (8 rows) into union region ----
    if (tid < 256) {
        int r = tid >> 5, c = (tid & 31) * 4;
        *reinterpret_cast<float4*>(&sh.u.c.sx[r][c]) =
            *reinterpret_cast<const float4*>(feat + (size_t)(rb + r)*128 + c);
    }
    __syncthreads();

    // ---- issue tile-0 loads early (hide under A' compute) ----
    const float* gm = msg2 + (size_t)b*NN*128;
    const float* ga = adj + (size_t)b*NN*NN + j0;
    float4 rs[8];
    unsigned int ra[2];
    {
        #pragma unroll
        for (int k = 0; k < 8; ++k) {
            int idx = tid + k*512;
            rs[k] = *reinterpret_cast<const float4*>(gm + (size_t)idx*4);
        }
        #pragma unroll
        for (int k = 0; k < 2; ++k) {
            int e = tid + k*512;
            float av = ga[(size_t)(e >> 3)*NN + (e & 7)];
            ra[k] = (av != 0.f) ? 0u : 0xFFC00000u;
        }
    }

    // ---- A': msg1, h1 for the 8 rows ----
    {
        const int m = tid & 127, rr = tid >> 7;   // rows rr*2, rr*2+1
        float a1v[2] = {0,0}, aov[2] = {0,0};
        #pragma unroll 4
        for (int k = 0; k < 128; ++k) {
            float wv1 = w1[k*128 + m], wvo = wo[k*128 + m];
            #pragma unroll
            for (int r = 0; r < 2; ++r) {
                float f = sh.u.c.sx[rr*2 + r][k];
                a1v[r] = fmaf(f, wv1, a1v[r]);
                aov[r] = fmaf(f, wvo, aov[r]);
            }
        }
        const float bb1 = b1[m], bbo = bo[m];
        #pragma unroll
        for (int r = 0; r < 2; ++r) {
            sh.m1[rr*2 + r][m] = a1v[r] + bb1;
            sh.hh[rr*2 + r][m] = aov[r] + bbo;
        }
    }
    __syncthreads();   // union feat reads done; m1/hh visible

    // ---- write tile 0 ----
    {
        float* base = &sh.u.sm2[0][0];
        #pragma unroll
        for (int k = 0; k < 8; ++k) {
            int idx = tid + k*512;
            *reinterpret_cast<float4*>(base + (size_t)idx*4) = rs[k];
        }
        #pragma unroll
        for (int k = 0; k < 2; ++k) {
            int e = tid + k*512;
            sh.adjm[e >> 3][e & 7] = ra[k];
        }
    }
    __syncthreads();

    // ---- B: masked max over 8 tiles of 128 i ----
    const int mg = tid & 31;            // m = mg*4
    const int jp = (tid >> 5) & 7;
    const int ih = tid >> 8;            // i-half within tile
    float acc[4] = {NEG_INF, NEG_INF, NEG_INF, NEG_INF};

    for (int t = 0; t < 8; ++t) {
        if (t < 7) {   // issue next-tile loads; land under this tile's compute
            const float* src = gm + (size_t)(t+1)*128*128;
            #pragma unroll
            for (int k = 0; k < 8; ++k) {
                int idx = tid + k*512;
                rs[k] = *reinterpret_cast<const float4*>(src + (size_t)idx*4);
            }
            #pragma unroll
            for (int k = 0; k < 2; ++k) {
                int e = tid + k*512;
                float av = ga[(size_t)((t+1)*128 + (e >> 3))*NN + (e & 7)];
                ra[k] = (av != 0.f) ? 0u : 0xFFC00000u;
            }
        }
        // compute this tile (ih half: 32 i-pairs)
        const int ib = ih * 64;
        #pragma unroll 4
        for (int p = 0; p < 32; ++p) {
            const int i = ib + 2*p;
            float4 v0 = *reinterpret_cast<const float4*>(&sh.u.sm2[i][mg*4]);
            float4 v1 = *reinterpret_cast<const float4*>(&sh.u.sm2[i+1][mg*4]);
            unsigned int p0 = sh.adjm[i][jp], p1 = sh.adjm[i+1][jp];
            // poisoned operand = quiet NaN -> dropped by IEEE maxnum (v_max3)
            acc[0] = fmaxf(fmaxf(acc[0], orf(v0.x, p0)), orf(v1.x, p1));
            acc[1] = fmaxf(fmaxf(acc[1], orf(v0.y, p0)), orf(v1.y, p1));
            acc[2] = fmaxf(fmaxf(acc[2], orf(v0.z, p0)), orf(v1.z, p1));
            acc[3] = fmaxf(fmaxf(acc[3], orf(v0.w, p0)), orf(v1.w, p1));
        }
        __syncthreads();
        if (t < 7) {
            float* base = &sh.u.sm2[0][0];
            #pragma unroll
            for (int k = 0; k < 8; ++k) {
                int idx = tid + k*512;
                *reinterpret_cast<float4*>(base + (size_t)idx*4) = rs[k];
            }
            #pragma unroll
            for (int k = 0; k < 2; ++k) {
                int e = tid + k*512;
                sh.adjm[e >> 3][e & 7] = ra[k];
            }
            __syncthreads();
        }
    }

    // ---- combine ih halves ----
    if (ih == 1) {
        const int s = tid - 256;
        #pragma unroll
        for (int w = 0; w < 4; ++w) sh.scratch[s][w] = acc[w];
    }
    __syncthreads();
    if (ih == 0) {
        #pragma unroll
        for (int w = 0; w < 4; ++w) acc[w] = fmaxf(acc[w], sh.scratch[tid][w]);
        // sx = relu(msg1 + max)   (-inf empty case -> relu 0)
        const int m = mg*4;
        #pragma unroll
        for (int w = 0; w < 4; ++w)
            sh.u.c.sx[jp][m + w] = fmaxf(sh.m1[jp][m + w] + acc[w], 0.f);
    }
    __syncthreads();

    // ---- C: MLP [32,64,64,128] + h1 add ----
    if (tid < 256) {   // L0: 128 -> 32
        int r = tid >> 5, c = tid & 31;
        float a = bm0[c];
        #pragma unroll 8
        for (int k = 0; k < 128; ++k) a = fmaf(sh.u.c.sx[r][k], wm0[k*32 + c], a);
        sh.u.c.sh0[r][c] = fmaxf(a, 0.f);
    }
    __syncthreads();
    {   // L1: 32 -> 64
        int r = tid >> 6, c = tid & 63;
        float a = bm1[c];
        #pragma unroll
        for (int k = 0; k < 32; ++k) a = fmaf(sh.u.c.sh0[r][k], wm1[k*64 + c], a);
        sh.u.c.sh1[r][c] = fmaxf(a, 0.f);
    }
    __syncthreads();
    {   // L2: 64 -> 64
        int r = tid >> 6, c = tid & 63;
        float a = bm2[c];
        #pragma unroll 8
        for (int k = 0; k < 64; ++k) a = fmaf(sh.u.c.sh1[r][k], wm2[k*64 + c], a);
        sh.u.c.sh2[r][c] = fmaxf(a, 0.f);
    }
    __syncthreads();
    {   // L3: 64 -> 128, rows r2 and r2+4, + h1, no relu
        int r2 = tid >> 7, c = tid & 127;
        float a0 = bm3[c], a1 = bm3[c];
        #pragma unroll 8
        for (int k = 0; k < 64; ++k) {
            float w = wm3[k*128 + c];
            a0 = fmaf(sh.u.c.sh2[r2][k],     w, a0);
            a1 = fmaf(sh.u.c.sh2[r2 + 4][k], w, a1);
        }
        out[(size_t)(rb + r2)*128 + c]     = sh.hh[r2][c]     + a0;
        out[(size_t)(rb + r2 + 4)*128 + c] = sh.hh[r2 + 4][c] + a1;
    }
}

extern "C" void kernel_launch(void* const* d_in, const int* in_sizes, int n_in,
                              void* d_out, int out_size, void* d_ws, size_t ws_size,
                              hipStream_t stream)
{
    const float* feat = (const float*)d_in[0];
    // d_in[1] = e_features (unused), d_in[2] = g_features (unused)
    const float* adj  = (const float*)d_in[3];
    const float* w1 = (const float*)d_in[4];   const float* b1 = (const float*)d_in[5];
    const float* w2 = (const float*)d_in[6];   const float* b2 = (const float*)d_in[7];
    const float* wo = (const float*)d_in[8];   const float* bo = (const float*)d_in[9];
    const float* wm0 = (const float*)d_in[10]; const float* bm0 = (const float*)d_in[11];
    const float* wm1 = (const float*)d_in[12]; const float* bm1 = (const float*)d_in[13];
    const float* wm2 = (const float*)d_in[14]; const float* bm2 = (const float*)d_in[15];
    const float* wm3 = (const float*)d_in[16]; const float* bm3 = (const float*)d_in[17];
    float* out = (float*)d_out;

    float* msg2 = (float*)d_ws;   // NROWS x 128 = 1 MB

    k1_msg2<<<256, 512, 0, stream>>>(feat, w2, b2, msg2);

    k2_fused<<<256, 512, 0, stream>>>(feat, adj, msg2,
        w1, b1, wo, bo, wm0, bm0, wm1, bm1, wm2, bm2, wm3, bm3, out);
}

// Round 7
// 41.778 us; speedup vs baseline: 3.0310x; 3.0310x over previous
//
#include <hip/hip_runtime.h>

#define NN 1024
#define NROWS 2048

#define NEG_INF (-__builtin_huge_valf())

__device__ __forceinline__ float orf(float v, unsigned int m) {
    return __uint_as_float(__float_as_uint(v) | m);
}

// ---------------- K1: msg2 = feat @ w2 + b2 ----------------------------------
// grid 512 x 256 thr; 4 rows/block.
__global__ __launch_bounds__(256) void k1_msg2(
    const float* __restrict__ feat, const float* __restrict__ w2,
    const float* __restrict__ b2, float* __restrict__ msg2)
{
    __shared__ float sf[4][128];
    const int tid = threadIdx.x;
    const int rb = blockIdx.x * 4;
    if (tid < 128) {
        int r = tid >> 5, c = (tid & 31) * 4;
        *reinterpret_cast<float4*>(&sf[r][c]) =
            *reinterpret_cast<const float4*>(feat + (size_t)(rb + r)*128 + c);
    }
    __syncthreads();
    const int m = tid & 127, rh = tid >> 7;     // rows rh*2, rh*2+1
    float a0 = 0.f, a1 = 0.f;
    #pragma unroll 4
    for (int k = 0; k < 128; ++k) {
        float wv = w2[k*128 + m];
        a0 = fmaf(sf[rh*2][k],   wv, a0);
        a1 = fmaf(sf[rh*2+1][k], wv, a1);
    }
    const float bb = b2[m];
    msg2[(size_t)(rb + rh*2)*128 + m]     = a0 + bb;
    msg2[(size_t)(rb + rh*2 + 1)*128 + m] = a1 + bb;
}

// ---------------- K2: msg1/h1 + ballot masks + reg-direct max + MLP ----------
// grid 256 linear (XCD-chunked: 32 consecutive j-tiles per XCD), 512 thr.
// Block owns 8 output rows (b, j0..j0+7). msg2 read straight from L2 to regs;
// masks as per-row u64 bitmaps from __ballot; acc[8j][4m] per thread.
struct K2S {
    union {
        float scratch[8][16][132];          // 67.6 KB strip-combine
        struct { float sf[8][128];          // A' feat stage
                 float sx[8][128];          // MLP input
                 float sh0[8][32]; float sh1[8][64]; float sh2[8][64]; } c;
    } u;
    unsigned long long adjm[128];           // 1 KB  row-bitmaps (8 j bits / row)
    float m1[8][128];                       // 4 KB
    float hh[8][128];                       // 4 KB
};

__global__ __launch_bounds__(512) void k2_fused(
    const float* __restrict__ feat, const float* __restrict__ adj,
    const float* __restrict__ msg2,
    const float* __restrict__ w1, const float* __restrict__ b1,
    const float* __restrict__ wo, const float* __restrict__ bo,
    const float* __restrict__ wm0, const float* __restrict__ bm0,
    const float* __restrict__ wm1, const float* __restrict__ bm1,
    const float* __restrict__ wm2, const float* __restrict__ bm2,
    const float* __restrict__ wm3, const float* __restrict__ bm3,
    float* __restrict__ out)
{
    __shared__ K2S sh;
    const int tid = threadIdx.x;
    // XCD-chunked swizzle: dispatch d -> orig (d&7)*32 + (d>>3); 256 % 8 == 0.
    const int orig = (blockIdx.x & 7) * 32 + (blockIdx.x >> 3);
    const int b  = orig >> 7;
    const int j0 = (orig & 127) * 8;
    const int rb = b * NN + j0;             // flat row base (8 rows)

    // ---- stage feat (8 rows); issue adj loads early ----
    if (tid < 256) {
        int r = tid >> 5, c = (tid & 31) * 4;
        *reinterpret_cast<float4*>(&sh.u.c.sf[r][c]) =
            *reinterpret_cast<const float4*>(feat + (size_t)(rb + r)*128 + c);
    }
    const float* ga = adj + (size_t)b*NN*NN + j0;
    float av[16];
    #pragma unroll
    for (int k = 0; k < 16; ++k) {
        int e = tid + k*512;
        av[k] = ga[(size_t)(e >> 3)*NN + (e & 7)];
    }
    __syncthreads();

    // ---- A': msg1, h1 for the 8 rows (adj loads land underneath) ----
    {
        const int m = tid & 127, rr = tid >> 7;   // rows rr*2, rr*2+1
        float a1v[2] = {0,0}, aov[2] = {0,0};
        #pragma unroll 4
        for (int k = 0; k < 128; ++k) {
            float wv1 = w1[k*128 + m], wvo = wo[k*128 + m];
            #pragma unroll
            for (int r = 0; r < 2; ++r) {
                float f = sh.u.c.sf[rr*2 + r][k];
                a1v[r] = fmaf(f, wv1, a1v[r]);
                aov[r] = fmaf(f, wvo, aov[r]);
            }
        }
        const float bb1 = b1[m], bbo = bo[m];
        #pragma unroll
        for (int r = 0; r < 2; ++r) {
            sh.m1[rr*2 + r][m] = a1v[r] + bb1;
            sh.hh[rr*2 + r][m] = aov[r] + bbo;
        }
    }
    // ---- pack adj bitmaps: bit ((i&7)*8 + jloc) of adjm[i>>3] ----
    #pragma unroll
    for (int k = 0; k < 16; ++k) {
        unsigned long long bal = __ballot(av[k] != 0.f);
        if ((tid & 63) == 0) sh.adjm[(tid + k*512) >> 6] = bal;
    }
    __syncthreads();

    // ---- reduction: acc[j][w] = max over this thread's 64-i strip ----
    const int mq = tid & 31;                // m-granule: m = mq*4
    const int s  = tid >> 5;                // strip 0..15 -> i = s*64 .. +63
    const float* gmb = msg2 + ((size_t)b*NN)*128 + mq*4;
    const int ib = s * 64;

    float acc[8][4];
    #pragma unroll
    for (int j = 0; j < 8; ++j)
        #pragma unroll
        for (int w = 0; w < 4; ++w) acc[j][w] = NEG_INF;

    float4 v0 = *reinterpret_cast<const float4*>(gmb + (size_t)ib*128);
    float4 v1 = *reinterpret_cast<const float4*>(gmb + (size_t)(ib+1)*128);
    #pragma unroll 4
    for (int p = 0; p < 32; ++p) {
        float4 n0, n1;
        if (p < 31) {
            n0 = *reinterpret_cast<const float4*>(gmb + (size_t)(ib + 2*p + 2)*128);
            n1 = *reinterpret_cast<const float4*>(gmb + (size_t)(ib + 2*p + 3)*128);
        }
        const int i = ib + 2*p;
        unsigned long long word = sh.adjm[i >> 3];
        unsigned int b0 = (unsigned int)(word >> (((2*p)  & 7) * 8)) & 0xFFu;
        unsigned int b1 = (unsigned int)(word >> (((2*p+1)& 7) * 8)) & 0xFFu;
        const float* f0 = reinterpret_cast<const float*>(&v0);
        const float* f1 = reinterpret_cast<const float*>(&v1);
        #pragma unroll
        for (int j = 0; j < 8; ++j) {
            unsigned int k0 = (((b0 >> j) & 1u) - 1u) & 0xFFC00000u;
            unsigned int k1 = (((b1 >> j) & 1u) - 1u) & 0xFFC00000u;
            #pragma unroll
            for (int w = 0; w < 4; ++w) {
                // poisoned operand = quiet NaN -> dropped by IEEE maxnum (v_max3)
                acc[j][w] = fmaxf(fmaxf(acc[j][w], orf(f0[w], k0)), orf(f1[w], k1));
            }
        }
        v0 = n0; v1 = n1;
    }

    // ---- strip combine via padded scratch ----
    #pragma unroll
    for (int j = 0; j < 8; ++j)
        *reinterpret_cast<float4*>(&sh.u.scratch[j][s][mq*4]) =
            make_float4(acc[j][0], acc[j][1], acc[j][2], acc[j][3]);
    __syncthreads();
    float val0, val1;
    {
        int e0 = tid, e1 = tid + 512;
        int ja = e0 >> 7, ma = e0 & 127;
        int jb = e1 >> 7, mb = e1 & 127;
        float x = NEG_INF, y = NEG_INF;
        #pragma unroll
        for (int t = 0; t < 16; ++t) {
            x = fmaxf(x, sh.u.scratch[ja][t][ma]);
            y = fmaxf(y, sh.u.scratch[jb][t][mb]);
        }
        val0 = fmaxf(sh.m1[ja][ma] + x, 0.f);   // -inf (empty) -> relu 0
        val1 = fmaxf(sh.m1[jb][mb] + y, 0.f);
    }
    __syncthreads();          // scratch reads done; sx overlays scratch
    sh.u.c.sx[tid >> 7][tid & 127] = val0;
    sh.u.c.sx[(tid + 512) >> 7][(tid + 512) & 127] = val1;
    __syncthreads();

    // ---- MLP [32,64,64,128] + h1 add ----
    if (tid < 256) {   // L0: 128 -> 32
        int r = tid >> 5, c = tid & 31;
        float a = bm0[c];
        #pragma unroll 8
        for (int k = 0; k < 128; ++k) a = fmaf(sh.u.c.sx[r][k], wm0[k*32 + c], a);
        sh.u.c.sh0[r][c] = fmaxf(a, 0.f);
    }
    __syncthreads();
    {   // L1: 32 -> 64
        int r = tid >> 6, c = tid & 63;
        float a = bm1[c];
        #pragma unroll
        for (int k = 0; k < 32; ++k) a = fmaf(sh.u.c.sh0[r][k], wm1[k*64 + c], a);
        sh.u.c.sh1[r][c] = fmaxf(a, 0.f);
    }
    __syncthreads();
    {   // L2: 64 -> 64
        int r = tid >> 6, c = tid & 63;
        float a = bm2[c];
        #pragma unroll 8
        for (int k = 0; k < 64; ++k) a = fmaf(sh.u.c.sh1[r][k], wm2[k*64 + c], a);
        sh.u.c.sh2[r][c] = fmaxf(a, 0.f);
    }
    __syncthreads();
    {   // L3: 64 -> 128, rows r2 and r2+4, + h1, no relu
        int r2 = tid >> 7, c = tid & 127;
        float a0 = bm3[c], a1 = bm3[c];
        #pragma unroll 8
        for (int k = 0; k < 64; ++k) {
            float w = wm3[k*128 + c];
            a0 = fmaf(sh.u.c.sh2[r2][k],     w, a0);
            a1 = fmaf(sh.u.c.sh2[r2 + 4][k], w, a1);
        }
        out[(size_t)(rb + r2)*128 + c]     = sh.hh[r2][c]     + a0;
        out[(size_t)(rb + r2 + 4)*128 + c] = sh.hh[r2 + 4][c] + a1;
    }
}

extern "C" void kernel_launch(void* const* d_in, const int* in_sizes, int n_in,
                              void* d_out, int out_size, void* d_ws, size_t ws_size,
                              hipStream_t stream)
{
    const float* feat = (const float*)d_in[0];
    // d_in[1] = e_features (unused), d_in[2] = g_features (unused)
    const float* adj  = (const float*)d_in[3];
    const float* w1 = (const float*)d_in[4];   const float* b1 = (const float*)d_in[5];
    const float* w2 = (const float*)d_in[6];   const float* b2 = (const float*)d_in[7];
    const float* wo = (const float*)d_in[8];   const float* bo = (const float*)d_in[9];
    const float* wm0 = (const float*)d_in[10]; const float* bm0 = (const float*)d_in[11];
    const float* wm1 = (const float*)d_in[12]; const float* bm1 = (const float*)d_in[13];
    const float* wm2 = (const float*)d_in[14]; const float* bm2 = (const float*)d_in[15];
    const float* wm3 = (const float*)d_in[16]; const float* bm3 = (const float*)d_in[17];
    float* out = (float*)d_out;

    float* msg2 = (float*)d_ws;   // NROWS x 128 = 1 MB

    k1_msg2<<<512, 256, 0, stream>>>(feat, w2, b2, msg2);

    k2_fused<<<256, 512, 0, stream>>>(feat, adj, msg2,
        w1, b1, wo, bo, wm0, bm0, wm1, bm1, wm2, bm2, wm3, bm3, out);
}

// Round 8
// 36.391 us; speedup vs baseline: 3.4797x; 1.1480x over previous
//
#include <hip/hip_runtime.h>

#define NN 1024
#define NROWS 2048

#define NEG_INF (-__builtin_huge_valf())

__device__ __forceinline__ float orf(float v, unsigned int m) {
    return __uint_as_float(__float_as_uint(v) | m);
}

// ---------------- K1: msg1 = F@w1+b1 ; msg2 = F@w2+b2 ; h1 = F@wo+bo ---------
// grid 512 x 256 thr; 4 rows/block (2+ blocks/CU).
__global__ __launch_bounds__(256) void k1_lin3(
    const float* __restrict__ feat,
    const float* __restrict__ w1, const float* __restrict__ b1,
    const float* __restrict__ w2, const float* __restrict__ b2,
    const float* __restrict__ wo, const float* __restrict__ bo,
    float* __restrict__ msg1, float* __restrict__ msg2, float* __restrict__ h1)
{
    __shared__ float sf[4][128];
    const int tid = threadIdx.x;
    const int rb = blockIdx.x * 4;
    if (tid < 128) {
        int r = tid >> 5, c = (tid & 31) * 4;
        *reinterpret_cast<float4*>(&sf[r][c]) =
            *reinterpret_cast<const float4*>(feat + (size_t)(rb + r) * 128 + c);
    }
    __syncthreads();
    const int m = tid & 127, rh = tid >> 7;   // rows rh*2, rh*2+1
    float a1[2] = {0,0}, a2[2] = {0,0}, ao[2] = {0,0};
    #pragma unroll 4
    for (int k = 0; k < 128; ++k) {
        float wv1 = w1[k*128 + m], wv2 = w2[k*128 + m], wvo = wo[k*128 + m];
        #pragma unroll
        for (int r = 0; r < 2; ++r) {
            float f = sf[rh*2 + r][k];
            a1[r] = fmaf(f, wv1, a1[r]);
            a2[r] = fmaf(f, wv2, a2[r]);
            ao[r] = fmaf(f, wvo, ao[r]);
        }
    }
    const float bb1 = b1[m], bb2 = b2[m], bbo = bo[m];
    #pragma unroll
    for (int r = 0; r < 2; ++r) {
        size_t row = rb + rh*2 + r;
        msg1[row*128 + m] = a1[r] + bb1;
        msg2[row*128 + m] = a2[r] + bb2;
        h1  [row*128 + m] = ao[r] + bbo;
    }
}

// ---------------- K2: pre-expanded poison masks + reg-direct max + MLP -------
// grid 256 (XCD-chunked), 512 thr, 64 KB LDS (1 block/CU).
// Block owns 8 output rows (b, j0..j0+7). msg2 straight from L2 to regs.
// adjp[ipair][j][2] = 0 / 0xFFC00000 built once; inner loop = 4 ds_b128 +
// or+max3 only (1.5 VALU/update).
struct K2S {
    union {
        float scratch[8][16][128];            // 64 KB strip-combine
        unsigned int adjp[512][8][2];         // 32 KB poison words
        struct { float sx[8][128]; float sh0[8][32];
                 float sh1[8][64]; float sh2[8][64]; } c;   // 9 KB MLP
    } u;
};

__global__ __launch_bounds__(512) void k2_fused(
    const float* __restrict__ adj, const float* __restrict__ msg2,
    const float* __restrict__ msg1, const float* __restrict__ h1v,
    const float* __restrict__ wm0, const float* __restrict__ bm0,
    const float* __restrict__ wm1, const float* __restrict__ bm1,
    const float* __restrict__ wm2, const float* __restrict__ bm2,
    const float* __restrict__ wm3, const float* __restrict__ bm3,
    float* __restrict__ out)
{
    __shared__ K2S sh;
    const int tid = threadIdx.x;
    // XCD-chunked swizzle (256 % 8 == 0 -> bijective)
    const int orig = (blockIdx.x & 7) * 32 + (blockIdx.x >> 3);
    const int b  = orig >> 7;
    const int j0 = (orig & 127) * 8;
    const int rb = b * NN + j0;               // flat row base (8 rows)

    // ---- load adj for the block's 8 columns (j0..j0+7), all 1024 i ----
    const float* ga = adj + (size_t)b*NN*NN + j0;
    float av[16];
    #pragma unroll
    for (int k = 0; k < 16; ++k) {
        int e = tid + k*512;
        av[k] = ga[(size_t)(e >> 3)*NN + (e & 7)];
    }
    // ---- build pre-expanded poison words: adjp[i>>1][j][i&1] ----
    unsigned int* ap = &sh.u.adjp[0][0][0];
    #pragma unroll
    for (int k = 0; k < 16; ++k) {
        int e = tid + k*512;
        int i = e >> 3, jl = e & 7;
        ap[(size_t)(i >> 1)*16 + jl*2 + (i & 1)] =
            (av[k] != 0.f) ? 0u : 0xFFC00000u;
    }
    __syncthreads();

    // ---- reduction: acc[j][w] over this thread's 64-i strip ----
    const int mq = tid & 31;                  // m = mq*4
    const int s  = tid >> 5;                  // strip 0..15 -> i = s*64..+63
    const float* gmb = msg2 + ((size_t)b*NN)*128 + mq*4;
    const int ib = s * 64;

    float acc[8][4];
    #pragma unroll
    for (int j = 0; j < 8; ++j)
        #pragma unroll
        for (int w = 0; w < 4; ++w) acc[j][w] = NEG_INF;

    float4 v0 = *reinterpret_cast<const float4*>(gmb + (size_t)ib*128);
    float4 v1 = *reinterpret_cast<const float4*>(gmb + (size_t)(ib+1)*128);
    #pragma unroll 4
    for (int p = 0; p < 32; ++p) {
        float4 n0, n1;
        if (p < 31) {
            n0 = *reinterpret_cast<const float4*>(gmb + (size_t)(ib + 2*p + 2)*128);
            n1 = *reinterpret_cast<const float4*>(gmb + (size_t)(ib + 2*p + 3)*128);
        }
        const int pg = s*32 + p;              // global i-pair index
        const uint4* mr = reinterpret_cast<const uint4*>(ap + (size_t)pg*16);
        uint4 q0 = mr[0], q1 = mr[1], q2 = mr[2], q3 = mr[3];
        unsigned int kk[16] = {q0.x,q0.y,q0.z,q0.w, q1.x,q1.y,q1.z,q1.w,
                               q2.x,q2.y,q2.z,q2.w, q3.x,q3.y,q3.z,q3.w};
        const float* f0 = reinterpret_cast<const float*>(&v0);
        const float* f1 = reinterpret_cast<const float*>(&v1);
        #pragma unroll
        for (int j = 0; j < 8; ++j) {
            unsigned int k0 = kk[2*j], k1 = kk[2*j + 1];
            #pragma unroll
            for (int w = 0; w < 4; ++w) {
                // poisoned operand = quiet NaN -> dropped by IEEE maxnum (v_max3)
                acc[j][w] = fmaxf(fmaxf(acc[j][w], orf(f0[w], k0)), orf(f1[w], k1));
            }
        }
        v0 = n0; v1 = n1;
    }

    // ---- strip combine (scratch overlays adjp; all reads done) ----
    __syncthreads();
    #pragma unroll
    for (int j = 0; j < 8; ++j)
        *reinterpret_cast<float4*>(&sh.u.scratch[j][s][mq*4]) =
            make_float4(acc[j][0], acc[j][1], acc[j][2], acc[j][3]);
    __syncthreads();
    float val0, val1;
    {
        int e0 = tid, e1 = tid + 512;
        int ja = e0 >> 7, ma = e0 & 127;
        int jb = e1 >> 7, mb = e1 & 127;
        float x = NEG_INF, y = NEG_INF;
        #pragma unroll
        for (int t = 0; t < 16; ++t) {
            x = fmaxf(x, sh.u.scratch[ja][t][ma]);
            y = fmaxf(y, sh.u.scratch[jb][t][mb]);
        }
        // msg1 rows straight from global (coalesced); -inf empty -> relu 0
        val0 = fmaxf(msg1[(size_t)(rb + ja)*128 + ma] + x, 0.f);
        val1 = fmaxf(msg1[(size_t)(rb + jb)*128 + mb] + y, 0.f);
    }
    __syncthreads();          // scratch reads done; sx overlays scratch
    sh.u.c.sx[tid >> 7][tid & 127] = val0;
    sh.u.c.sx[(tid + 512) >> 7][(tid + 512) & 127] = val1;
    __syncthreads();

    // ---- MLP [32,64,64,128] + h1 add ----
    if (tid < 256) {   // L0: 128 -> 32
        int r = tid >> 5, c = tid & 31;
        float a = bm0[c];
        #pragma unroll 8
        for (int k = 0; k < 128; ++k) a = fmaf(sh.u.c.sx[r][k], wm0[k*32 + c], a);
        sh.u.c.sh0[r][c] = fmaxf(a, 0.f);
    }
    __syncthreads();
    {   // L1: 32 -> 64
        int r = tid >> 6, c = tid & 63;
        float a = bm1[c];
        #pragma unroll
        for (int k = 0; k < 32; ++k) a = fmaf(sh.u.c.sh0[r][k], wm1[k*64 + c], a);
        sh.u.c.sh1[r][c] = fmaxf(a, 0.f);
    }
    __syncthreads();
    {   // L2: 64 -> 64
        int r = tid >> 6, c = tid & 63;
        float a = bm2[c];
        #pragma unroll 8
        for (int k = 0; k < 64; ++k) a = fmaf(sh.u.c.sh1[r][k], wm2[k*64 + c], a);
        sh.u.c.sh2[r][c] = fmaxf(a, 0.f);
    }
    __syncthreads();
    {   // L3: 64 -> 128, rows r2 and r2+4, + h1 (global), no relu
        int r2 = tid >> 7, c = tid & 127;
        float a0 = bm3[c], a1 = bm3[c];
        #pragma unroll 8
        for (int k = 0; k < 64; ++k) {
            float w = wm3[k*128 + c];
            a0 = fmaf(sh.u.c.sh2[r2][k],     w, a0);
            a1 = fmaf(sh.u.c.sh2[r2 + 4][k], w, a1);
        }
        out[(size_t)(rb + r2)*128 + c]     = h1v[(size_t)(rb + r2)*128 + c]     + a0;
        out[(size_t)(rb + r2 + 4)*128 + c] = h1v[(size_t)(rb + r2 + 4)*128 + c] + a1;
    }
}

extern "C" void kernel_launch(void* const* d_in, const int* in_sizes, int n_in,
                              void* d_out, int out_size, void* d_ws, size_t ws_size,
                              hipStream_t stream)
{
    const float* feat = (const float*)d_in[0];
    // d_in[1] = e_features (unused), d_in[2] = g_features (unused)
    const float* adj  = (const float*)d_in[3];
    const float* w1 = (const float*)d_in[4];   const float* b1 = (const float*)d_in[5];
    const float* w2 = (const float*)d_in[6];   const float* b2 = (const float*)d_in[7];
    const float* wo = (const float*)d_in[8];   const float* bo = (const float*)d_in[9];
    const float* wm0 = (const float*)d_in[10]; const float* bm0 = (const float*)d_in[11];
    const float* wm1 = (const float*)d_in[12]; const float* bm1 = (const float*)d_in[13];
    const float* wm2 = (const float*)d_in[14]; const float* bm2 = (const float*)d_in[15];
    const float* wm3 = (const float*)d_in[16]; const float* bm3 = (const float*)d_in[17];
    float* out = (float*)d_out;

    const size_t MAT = (size_t)NROWS * 128;
    float* msg1 = (float*)d_ws;
    float* msg2 = msg1 + MAT;
    float* h1v  = msg1 + 2*MAT;

    k1_lin3<<<512, 256, 0, stream>>>(feat, w1, b1, w2, b2, wo, bo, msg1, msg2, h1v);

    k2_fused<<<256, 512, 0, stream>>>(adj, msg2, msg1, h1v,
        wm0, bm0, wm1, bm1, wm2, bm2, wm3, bm3, out);
}